// Round 8
// baseline (204.733 us; speedup 1.0000x reference)
//
#include <hip/hip_runtime.h>

#define NPIX (512*512)

// ---------------------------------------------------------------------------
// Init kernel: coef[path][a][b][kq] = 0.5 * tp_w * Cr  (padded k-runs: 12/16).
// Path offsets (floats): {0,972,2268,3672,5544,6948,8820,10848}, 13552 total.
// ---------------------------------------------------------------------------

static __device__ __forceinline__ int qcol(int l, int c, int* row, double* re, double* im) {
  const double S = 0.70710678118654752440;
  int p = c - l;
  if (p == 0) { row[0] = l; re[0] = 1.0; im[0] = 0.0; return 1; }
  if (p > 0) {
    row[0] = l - p; re[0] = S;                 im[0] = 0.0;
    row[1] = l + p; re[1] = (p & 1) ? -S : S;  im[1] = 0.0;
    return 2;
  }
  int a = -p;
  row[0] = l - a; re[0] = 0.0; im[0] = -S;
  row[1] = l + a; re[1] = 0.0; im[1] = (a & 1) ? -S : S;
  return 2;
}

__global__ void w3j_init(const float* __restrict__ tpw, float* __restrict__ coef) {
  __shared__ double sC[13*13*13];
  __shared__ double sfact[20];
  const int p = blockIdx.x;
  const int la = (p & 4) ? 6 : 4, lb = (p & 2) ? 6 : 4, lc = (p & 1) ? 6 : 4;
  const int na = 2*la+1, nb = 2*lb+1, nc = 2*lc+1, ncp = (nc + 3) & ~3;
  if (threadIdx.x == 0) {
    double f = 1.0; sfact[0] = 1.0;
    for (int i = 1; i < 20; ++i) { f *= (double)i; sfact[i] = f; }
  }
  int off = 0;
  for (int q = 0; q < p; ++q)
    off += ((q&4)?13:9) * ((q&2)?13:9) * ((q&1)?16:12);
  for (int e = threadIdx.x; e < na*nb*nc; e += blockDim.x) sC[e] = 0.0;
  __syncthreads();
  for (int e = threadIdx.x; e < na*nb; e += blockDim.x) {
    int i = e / nb, j = e % nb;
    int m1 = i - la, m2 = j - lb, m3 = m1 + m2;
    if (m3 < -lc || m3 > lc) continue;
    double pre = sqrt((2.0*lc + 1.0) * sfact[lc+la-lb] * sfact[lc-la+lb] * sfact[la+lb-lc] / sfact[la+lb+lc+1]);
    pre *= sqrt(sfact[lc+m3]*sfact[lc-m3]*sfact[la-m1]*sfact[la+m1]*sfact[lb-m2]*sfact[lb+m2]);
    double s = 0.0;
    for (int k = 0; k <= la + lb - lc; ++k) {
      int d2 = la - m1 - k, d3 = lb + m2 - k, d4 = lc - lb + m1 + k, d5 = lc - la - m2 + k;
      if (d2 < 0 || d3 < 0 || d4 < 0 || d5 < 0) continue;
      s += ((k & 1) ? -1.0 : 1.0) /
           (sfact[k]*sfact[la+lb-lc-k]*sfact[d2]*sfact[d3]*sfact[d4]*sfact[d5]);
    }
    sC[(i*nb + j)*nc + (lc + m3)] = pre * s;
  }
  __syncthreads();
  const double PH = (((la/2)&1)?-1.0:1.0)*(((lb/2)&1)?-1.0:1.0)*(((lc/2)&1)?-1.0:1.0);
  const double scale = 0.5 * (double)tpw[p] * PH;
  for (int e = threadIdx.x; e < na*nb*ncp; e += blockDim.x) {
    int a = e / (nb*ncp), rem = e % (nb*ncp), b = rem / ncp, c = rem % ncp;
    float val = 0.0f;
    if (c < nc) {
      int r1[2]; double u1r[2], u1i[2]; int n1 = qcol(la, a, r1, u1r, u1i);
      int r2[2]; double u2r[2], u2i[2]; int n2 = qcol(lb, b, r2, u2r, u2i);
      int r3[2]; double u3r[2], u3i[2]; int n3 = qcol(lc, c, r3, u3r, u3i);
      double acc = 0.0;
      for (int u = 0; u < n1; ++u)
        for (int v = 0; v < n2; ++v) {
          double Rr = u1r[u]*u2r[v] - u1i[u]*u2i[v];
          double Ri = u1r[u]*u2i[v] + u1i[u]*u2r[v];
          for (int w = 0; w < n3; ++w) {
            double cv = sC[(r1[u]*nb + r2[v])*nc + r3[w]];
            acc += (Rr*u3r[w] + Ri*u3i[w]) * cv;
          }
        }
      val = (float)(scale * acc);
    }
    coef[off + e] = val;
  }
}

static __device__ __forceinline__ void fma4(float4& a, const float4 c, const float s) {
  a.x = fmaf(c.x, s, a.x); a.y = fmaf(c.y, s, a.y);
  a.z = fmaf(c.z, s, a.z); a.w = fmaf(c.w, s, a.w);
}

// ---------------------------------------------------------------------------
// K1: zcalc. Block = 8 low-res pixels (128 thr), grid 2048, LDS 24 KB.
//  P1 (entries 154, grid-stride): cR once in regs, M -> LDS.
//  P2 (56 thr = 8p x 7kq): z[9] in regs -> GLOBAL z (16.5 MB in ws).
// z layout: zg[pix][nb(9)][28 words], quad-aligned.
// ---------------------------------------------------------------------------
__global__ __launch_bounds__(128, 3) void zcalc(
    const float* __restrict__ f4, const float* __restrict__ f6,
    const float* __restrict__ coef, float* __restrict__ zg) {
  __shared__ float Mf[8 * 620];    // 19840 B
  __shared__ float xh[3*10*28];    // 3360 B packed halo
  __shared__ float xT[22*8];       // 704 B

  const int tid = threadIdx.x;
  const int ry  = blockIdx.x >> 4;
  const int cx0 = (blockIdx.x & 15) * 8;

  for (int e = tid; e < 660; e += 128) {       // halo 3x10x22
    int r = e / 220, rem = e - r*220;
    int c = rem / 22, w = rem - c*22;
    int rr = min(127, max(0, ry - 1 + r));
    int cc = min(127, max(0, cx0 - 1 + c));
    float v = (w < 9) ? f4[(rr*128 + cc)*9 + w] : f6[(rr*128 + cc)*13 + (w - 9)];
    xh[(r*10 + c)*28 + (w < 9 ? w : w + 3)] = v;
  }
  for (int e = tid; e < 180; e += 128) {       // zero pads
    int pix = e / 6, s = e - pix*6;
    xh[pix*28 + (s < 3 ? 9 + s : 22 + s)] = 0.f;
  }
  for (int e = tid; e < 176; e += 128) {       // xT[c][p], 8 pixels
    int c = e >> 3, p = e & 7;
    int pix = ry*128 + cx0 + p;
    xT[c*8 + p] = (c < 9) ? f4[pix*9 + c] : f6[pix*13 + (c - 9)];
  }
  __syncthreads();

  // ---- P1: M = C . x ----
  for (int ent = tid; ent < 154; ent += 128) {
    int cls, jj, kqc;
    if (ent < 27)       { cls = 0; jj = ent / 3;         kqc = ent % 3; }
    else if (ent < 63)  { cls = 1; jj = (ent - 27) / 4;  kqc = (ent - 27) % 4; }
    else if (ent < 102) { cls = 2; jj = (ent - 63) / 3;  kqc = (ent - 63) % 3; }
    else                { cls = 3; jj = (ent - 102) / 4; kqc = (ent - 102) % 4; }
    const int ncp  = (cls == 0 || cls == 2) ? 12 : 16;
    const int str  = (cls == 0) ? 108 : (cls == 1) ? 144 : (cls == 2) ? 156 : 208;
    const int off4 = (cls == 0) ? 0    : (cls == 1) ? 972  : (cls == 2) ? 2268 : 3672;
    const int off6 = (cls == 0) ? 5544 : (cls == 1) ? 6948 : (cls == 2) ? 8820 : 10848;
    const int base4 = off4 + jj*ncp + 4*kqc;
    const int base6 = off6 + jj*ncp + 4*kqc;
    const int j   = (cls >= 2) ? 9 + jj : jj;
    const int kqu = (cls == 0 || cls == 2) ? kqc : 3 + kqc;

    float4 cR[22];
#pragma unroll
    for (int i = 0; i < 9; ++i)  cR[i]     = *(const float4*)(coef + base4 + i*str);
#pragma unroll
    for (int i = 0; i < 13; ++i) cR[9 + i] = *(const float4*)(coef + base6 + i*str);

    float4 acc[8];
#pragma unroll
    for (int p8 = 0; p8 < 8; ++p8) acc[p8] = make_float4(0.f, 0.f, 0.f, 0.f);
#pragma unroll
    for (int i = 0; i < 22; ++i) {
      float4 xa = *(const float4*)(&xT[i*8]);
      float4 xb = *(const float4*)(&xT[i*8 + 4]);
      fma4(acc[0], cR[i], xa.x); fma4(acc[1], cR[i], xa.y);
      fma4(acc[2], cR[i], xa.z); fma4(acc[3], cR[i], xa.w);
      fma4(acc[4], cR[i], xb.x); fma4(acc[5], cR[i], xb.y);
      fma4(acc[6], cR[i], xb.z); fma4(acc[7], cR[i], xb.w);
    }
    const int mo = j*28 + kqu*4;
#pragma unroll
    for (int p8 = 0; p8 < 8; ++p8)
      *(float4*)(&Mf[p8*620 + mo]) = acc[p8];
  }
  __syncthreads();

  // ---- P2: z[nb] = x_nb^T . M_p -> global ----
  const int p   = tid >> 3;
  const int kq  = tid & 7;
  if (tid < 64 && kq < 7) {
    const float* Mp = &Mf[p*620 + 4*kq];
    float4 m[22];
#pragma unroll
    for (int jx = 0; jx < 22; ++jx) m[jx] = *(const float4*)(Mp + jx*28);

    float4 z[9];
#pragma unroll
    for (int rs = 0; rs < 3; ++rs) {
#pragma unroll
      for (int cs = 0; cs < 3; ++cs) {
        const float* xb = &xh[(rs*10 + p + cs)*28];
        float4 x0 = *(const float4*)(xb);
        float4 x1 = *(const float4*)(xb + 4);
        float4 x2 = *(const float4*)(xb + 8);
        float4 x3 = *(const float4*)(xb + 12);
        float4 x4 = *(const float4*)(xb + 16);
        float4 x5 = *(const float4*)(xb + 20);
        float4 x6 = *(const float4*)(xb + 24);
        float4 t = make_float4(0.f, 0.f, 0.f, 0.f);
        fma4(t, m[0],  x0.x); fma4(t, m[1],  x0.y); fma4(t, m[2],  x0.z); fma4(t, m[3],  x0.w);
        fma4(t, m[4],  x1.x); fma4(t, m[5],  x1.y); fma4(t, m[6],  x1.z); fma4(t, m[7],  x1.w);
        fma4(t, m[8],  x2.x);
        fma4(t, m[9],  x3.x); fma4(t, m[10], x3.y); fma4(t, m[11], x3.z); fma4(t, m[12], x3.w);
        fma4(t, m[13], x4.x); fma4(t, m[14], x4.y); fma4(t, m[15], x4.z); fma4(t, m[16], x4.w);
        fma4(t, m[17], x5.x); fma4(t, m[18], x5.y); fma4(t, m[19], x5.z); fma4(t, m[20], x5.w);
        fma4(t, m[21], x6.x);
        z[rs*3 + cs] = t;
      }
    }
    float* zb = zg + (ry*128 + cx0 + p)*252 + 4*kq;
#pragma unroll
    for (int nb = 0; nb < 9; ++nb)
      *(float4*)(zb + nb*28) = z[nb];
  }
}

// ---------------------------------------------------------------------------
// K2: combine. One thread per hi-res pixel; no LDS, no barriers.
// out = A00*z[C] + A01*z[col] + A10*z[row] + A11*z[diag] + x ; scalar stores.
// ---------------------------------------------------------------------------
__global__ __launch_bounds__(256) void comb(
    const float* __restrict__ f4, const float* __restrict__ f6,
    const float* __restrict__ sw, const float* __restrict__ zg,
    float* __restrict__ out) {
  const int n  = blockIdx.x * 256 + threadIdx.x;
  const int Yh = n >> 9, Xh = n & 511;
  const int ry = Yh >> 2, cx = Xh >> 2;
  const int dy = Yh & 3,  dx = Xh & 3;

  const float wrT = (dy == 0 && ry != 0)   ? 1.f : 0.f;
  const float wrB = (dy == 3 && ry != 127) ? 1.f : 0.f;
  const float wcL = (dx == 0 && cx != 0)   ? 1.f : 0.f;
  const float wcR = (dx == 3 && cx != 127) ? 1.f : 0.f;

  float A00 = 0.f, A01 = 0.f, A10 = 0.f, A11 = 0.f;
#pragma unroll
  for (int t9 = 0; t9 < 9; ++t9) {
    const int ddy = t9 / 3, ddx = t9 % 3;
    const float wr = (ddy == 0) ? wrT : ((ddy == 2) ? wrB : 0.f);
    const float wc = (ddx == 0) ? wcL : ((ddx == 2) ? wcR : 0.f);
    const float s = sw[t9];
    A00 += (1.f - wr) * (1.f - wc) * s;
    A01 += (1.f - wr) * wc * s;
    A10 += wr * (1.f - wc) * s;
    A11 += wr * wc * s;
  }

  const int pix = ry*128 + cx;
  const float* zb = zg + pix*252;
  const int cnb = (dx == 0) ? 3 : 5;
  const int rnb = (dy == 0) ? 1 : 7;
  const int dnb = ((dy == 0) ? 0 : 6) + ((dx == 0) ? 0 : 2);

  float* o4 = out + n*9;
  float* o6 = out + NPIX*9 + n*13;
  const float* x4 = f4 + pix*9;
  const float* x6 = f6 + pix*13;

#pragma unroll
  for (int kq = 0; kq < 7; ++kq) {
    float4 zC = *(const float4*)(zb + 4*28   + 4*kq);
    float4 z1 = *(const float4*)(zb + cnb*28 + 4*kq);
    float4 z2 = *(const float4*)(zb + rnb*28 + 4*kq);
    float4 z3 = *(const float4*)(zb + dnb*28 + 4*kq);
    float o0 = fmaf(A00, zC.x, fmaf(A01, z1.x, fmaf(A10, z2.x, A11 * z3.x)));
    float o1 = fmaf(A00, zC.y, fmaf(A01, z1.y, fmaf(A10, z2.y, A11 * z3.y)));
    float o2 = fmaf(A00, zC.z, fmaf(A01, z1.z, fmaf(A10, z2.z, A11 * z3.z)));
    float o3 = fmaf(A00, zC.w, fmaf(A01, z1.w, fmaf(A10, z2.w, A11 * z3.w)));
    if (kq < 2) {
      const int b = 4*kq;
      o4[b]   = o0 + x4[b];
      o4[b+1] = o1 + x4[b+1];
      o4[b+2] = o2 + x4[b+2];
      o4[b+3] = o3 + x4[b+3];
    } else if (kq == 2) {
      o4[8] = o0 + x4[8];
    } else if (kq < 6) {
      const int b = 4*(kq - 3);
      o6[b]   = o0 + x6[b];
      o6[b+1] = o1 + x6[b+1];
      o6[b+2] = o2 + x6[b+2];
      o6[b+3] = o3 + x6[b+3];
    } else {
      o6[12] = o0 + x6[12];
    }
  }
}

extern "C" void kernel_launch(void* const* d_in, const int* in_sizes, int n_in,
                              void* d_out, int out_size, void* d_ws, size_t ws_size,
                              hipStream_t stream) {
  const float* f4  = (const float*)d_in[0];
  const float* f6  = (const float*)d_in[1];
  const float* sw  = (const float*)d_in[2];
  const float* tpw = (const float*)d_in[3];
  float* coef = (float*)d_ws;                 // 13552 floats (pad to 16384)
  float* zg   = (float*)d_ws + 16384;         // 16384*252 floats = 16.5 MB
  float* out  = (float*)d_out;

  hipLaunchKernelGGL(w3j_init, dim3(8), dim3(256), 0, stream, tpw, coef);
  hipLaunchKernelGGL(zcalc, dim3(2048), dim3(128), 0, stream, f4, f6, coef, zg);
  hipLaunchKernelGGL(comb, dim3(1024), dim3(256), 0, stream, f4, f6, sw, zg, out);
}

// Round 9
// 102.165 us; speedup vs baseline: 2.0040x; 2.0040x over previous
//
#include <hip/hip_runtime.h>

#define NPIX (512*512)

// ---------------------------------------------------------------------------
// Init kernel: coef[path][a][b][kq] = 0.5 * tp_w * Cr  (padded k-runs: 12/16).
// Path offsets (floats): {0,972,2268,3672,5544,6948,8820,10848}, 13552 total.
// ---------------------------------------------------------------------------

static __device__ __forceinline__ int qcol(int l, int c, int* row, double* re, double* im) {
  const double S = 0.70710678118654752440;
  int p = c - l;
  if (p == 0) { row[0] = l; re[0] = 1.0; im[0] = 0.0; return 1; }
  if (p > 0) {
    row[0] = l - p; re[0] = S;                 im[0] = 0.0;
    row[1] = l + p; re[1] = (p & 1) ? -S : S;  im[1] = 0.0;
    return 2;
  }
  int a = -p;
  row[0] = l - a; re[0] = 0.0; im[0] = -S;
  row[1] = l + a; re[1] = 0.0; im[1] = (a & 1) ? -S : S;
  return 2;
}

__global__ void w3j_init(const float* __restrict__ tpw, float* __restrict__ coef) {
  __shared__ double sC[13*13*13];
  __shared__ double sfact[20];
  const int p = blockIdx.x;
  const int la = (p & 4) ? 6 : 4, lb = (p & 2) ? 6 : 4, lc = (p & 1) ? 6 : 4;
  const int na = 2*la+1, nb = 2*lb+1, nc = 2*lc+1, ncp = (nc + 3) & ~3;
  if (threadIdx.x == 0) {
    double f = 1.0; sfact[0] = 1.0;
    for (int i = 1; i < 20; ++i) { f *= (double)i; sfact[i] = f; }
  }
  int off = 0;
  for (int q = 0; q < p; ++q)
    off += ((q&4)?13:9) * ((q&2)?13:9) * ((q&1)?16:12);
  for (int e = threadIdx.x; e < na*nb*nc; e += blockDim.x) sC[e] = 0.0;
  __syncthreads();
  for (int e = threadIdx.x; e < na*nb; e += blockDim.x) {
    int i = e / nb, j = e % nb;
    int m1 = i - la, m2 = j - lb, m3 = m1 + m2;
    if (m3 < -lc || m3 > lc) continue;
    double pre = sqrt((2.0*lc + 1.0) * sfact[lc+la-lb] * sfact[lc-la+lb] * sfact[la+lb-lc] / sfact[la+lb+lc+1]);
    pre *= sqrt(sfact[lc+m3]*sfact[lc-m3]*sfact[la-m1]*sfact[la+m1]*sfact[lb-m2]*sfact[lb+m2]);
    double s = 0.0;
    for (int k = 0; k <= la + lb - lc; ++k) {
      int d2 = la - m1 - k, d3 = lb + m2 - k, d4 = lc - lb + m1 + k, d5 = lc - la - m2 + k;
      if (d2 < 0 || d3 < 0 || d4 < 0 || d5 < 0) continue;
      s += ((k & 1) ? -1.0 : 1.0) /
           (sfact[k]*sfact[la+lb-lc-k]*sfact[d2]*sfact[d3]*sfact[d4]*sfact[d5]);
    }
    sC[(i*nb + j)*nc + (lc + m3)] = pre * s;
  }
  __syncthreads();
  const double PH = (((la/2)&1)?-1.0:1.0)*(((lb/2)&1)?-1.0:1.0)*(((lc/2)&1)?-1.0:1.0);
  const double scale = 0.5 * (double)tpw[p] * PH;
  for (int e = threadIdx.x; e < na*nb*ncp; e += blockDim.x) {
    int a = e / (nb*ncp), rem = e % (nb*ncp), b = rem / ncp, c = rem % ncp;
    float val = 0.0f;
    if (c < nc) {
      int r1[2]; double u1r[2], u1i[2]; int n1 = qcol(la, a, r1, u1r, u1i);
      int r2[2]; double u2r[2], u2i[2]; int n2 = qcol(lb, b, r2, u2r, u2i);
      int r3[2]; double u3r[2], u3i[2]; int n3 = qcol(lc, c, r3, u3r, u3i);
      double acc = 0.0;
      for (int u = 0; u < n1; ++u)
        for (int v = 0; v < n2; ++v) {
          double Rr = u1r[u]*u2r[v] - u1i[u]*u2i[v];
          double Ri = u1r[u]*u2i[v] + u1i[u]*u2r[v];
          for (int w = 0; w < n3; ++w) {
            double cv = sC[(r1[u]*nb + r2[v])*nc + r3[w]];
            acc += (Rr*u3r[w] + Ri*u3i[w]) * cv;
          }
        }
      val = (float)(scale * acc);
    }
    coef[off + e] = val;
  }
}

static __device__ __forceinline__ void fma4(float4& a, const float4 c, const float s) {
  a.x = fmaf(c.x, s, a.x); a.y = fmaf(c.y, s, a.y);
  a.z = fmaf(c.z, s, a.z); a.w = fmaf(c.w, s, a.w);
}

// ---------------------------------------------------------------------------
// K1: zcalc. Block = 8 low-res pixels (128 thr), grid 2048, LDS 24 KB.
// REGISTER BUDGET (r8 lesson: launch_bounds(128,3) capped VGPR=84 -> 450 MB
// of scratch spill): no min-waves bound; C and M processed in 9/13 chunks so
// peak float4 arrays are 13+8 (P1) and 13+9 (P2) ~= 120 VGPR.
// ---------------------------------------------------------------------------
__global__ __launch_bounds__(128, 1) void zcalc(
    const float* __restrict__ f4, const float* __restrict__ f6,
    const float* __restrict__ coef, float* __restrict__ zg) {
  __shared__ float Mf[8 * 620];    // 19840 B
  __shared__ float xh[3*10*28];    // 3360 B packed halo
  __shared__ float xT[22*8];       // 704 B

  const int tid = threadIdx.x;
  const int ry  = blockIdx.x >> 4;
  const int cx0 = (blockIdx.x & 15) * 8;

  for (int e = tid; e < 660; e += 128) {       // halo 3x10x22
    int r = e / 220, rem = e - r*220;
    int c = rem / 22, w = rem - c*22;
    int rr = min(127, max(0, ry - 1 + r));
    int cc = min(127, max(0, cx0 - 1 + c));
    float v = (w < 9) ? f4[(rr*128 + cc)*9 + w] : f6[(rr*128 + cc)*13 + (w - 9)];
    xh[(r*10 + c)*28 + (w < 9 ? w : w + 3)] = v;
  }
  for (int e = tid; e < 180; e += 128) {       // zero pads
    int pix = e / 6, s = e - pix*6;
    xh[pix*28 + (s < 3 ? 9 + s : 22 + s)] = 0.f;
  }
  for (int e = tid; e < 176; e += 128) {       // xT[c][p], 8 pixels
    int c = e >> 3, p = e & 7;
    int pix = ry*128 + cx0 + p;
    xT[c*8 + p] = (c < 9) ? f4[pix*9 + c] : f6[pix*13 + (c - 9)];
  }
  __syncthreads();

  // ---- P1: M = C . x  (chunked C: 9 quads then 13 quads) ----
  for (int ent = tid; ent < 154; ent += 128) {
    int cls, jj, kqc;
    if (ent < 27)       { cls = 0; jj = ent / 3;         kqc = ent % 3; }
    else if (ent < 63)  { cls = 1; jj = (ent - 27) / 4;  kqc = (ent - 27) % 4; }
    else if (ent < 102) { cls = 2; jj = (ent - 63) / 3;  kqc = (ent - 63) % 3; }
    else                { cls = 3; jj = (ent - 102) / 4; kqc = (ent - 102) % 4; }
    const int ncp  = (cls == 0 || cls == 2) ? 12 : 16;
    const int str  = (cls == 0) ? 108 : (cls == 1) ? 144 : (cls == 2) ? 156 : 208;
    const int off4 = (cls == 0) ? 0    : (cls == 1) ? 972  : (cls == 2) ? 2268 : 3672;
    const int off6 = (cls == 0) ? 5544 : (cls == 1) ? 6948 : (cls == 2) ? 8820 : 10848;
    const int base4 = off4 + jj*ncp + 4*kqc;
    const int base6 = off6 + jj*ncp + 4*kqc;
    const int j   = (cls >= 2) ? 9 + jj : jj;
    const int kqu = (cls == 0 || cls == 2) ? kqc : 3 + kqc;

    float4 acc[8];
#pragma unroll
    for (int p8 = 0; p8 < 8; ++p8) acc[p8] = make_float4(0.f, 0.f, 0.f, 0.f);

    {   // chunk A: la=4 rows (9 quads live)
      float4 c9[9];
#pragma unroll
      for (int i = 0; i < 9; ++i) c9[i] = *(const float4*)(coef + base4 + i*str);
#pragma unroll
      for (int i = 0; i < 9; ++i) {
        float4 xa = *(const float4*)(&xT[i*8]);
        float4 xb = *(const float4*)(&xT[i*8 + 4]);
        fma4(acc[0], c9[i], xa.x); fma4(acc[1], c9[i], xa.y);
        fma4(acc[2], c9[i], xa.z); fma4(acc[3], c9[i], xa.w);
        fma4(acc[4], c9[i], xb.x); fma4(acc[5], c9[i], xb.y);
        fma4(acc[6], c9[i], xb.z); fma4(acc[7], c9[i], xb.w);
      }
    }
    {   // chunk B: la=6 rows (13 quads live)
      float4 c13[13];
#pragma unroll
      for (int i = 0; i < 13; ++i) c13[i] = *(const float4*)(coef + base6 + i*str);
#pragma unroll
      for (int i = 0; i < 13; ++i) {
        float4 xa = *(const float4*)(&xT[(9 + i)*8]);
        float4 xb = *(const float4*)(&xT[(9 + i)*8 + 4]);
        fma4(acc[0], c13[i], xa.x); fma4(acc[1], c13[i], xa.y);
        fma4(acc[2], c13[i], xa.z); fma4(acc[3], c13[i], xa.w);
        fma4(acc[4], c13[i], xb.x); fma4(acc[5], c13[i], xb.y);
        fma4(acc[6], c13[i], xb.z); fma4(acc[7], c13[i], xb.w);
      }
    }
    const int mo = j*28 + kqu*4;
#pragma unroll
    for (int p8 = 0; p8 < 8; ++p8)
      *(float4*)(&Mf[p8*620 + mo]) = acc[p8];
  }
  __syncthreads();

  // ---- P2: z[nb] = x_nb^T . M_p -> global  (chunked M: 9 then 13 quads) ----
  const int p  = tid >> 3;
  const int kq = tid & 7;
  if (tid < 64 && kq < 7) {
    const float* Mp = &Mf[p*620 + 4*kq];

    float4 z[9];
#pragma unroll
    for (int nb = 0; nb < 9; ++nb) z[nb] = make_float4(0.f, 0.f, 0.f, 0.f);

    {   // chunk A: features 0..8 (x quads 0..2)
      float4 mA[9];
#pragma unroll
      for (int jx = 0; jx < 9; ++jx) mA[jx] = *(const float4*)(Mp + jx*28);
#pragma unroll
      for (int rs = 0; rs < 3; ++rs) {
#pragma unroll
        for (int cs = 0; cs < 3; ++cs) {
          const float* xb = &xh[(rs*10 + p + cs)*28];
          float4 x0 = *(const float4*)(xb);
          float4 x1 = *(const float4*)(xb + 4);
          float4 x2 = *(const float4*)(xb + 8);
          float4 t = z[rs*3 + cs];
          fma4(t, mA[0], x0.x); fma4(t, mA[1], x0.y); fma4(t, mA[2], x0.z); fma4(t, mA[3], x0.w);
          fma4(t, mA[4], x1.x); fma4(t, mA[5], x1.y); fma4(t, mA[6], x1.z); fma4(t, mA[7], x1.w);
          fma4(t, mA[8], x2.x);
          z[rs*3 + cs] = t;
        }
      }
    }
    {   // chunk B: features 9..21 (x quads 3..6)
      float4 mB[13];
#pragma unroll
      for (int jx = 0; jx < 13; ++jx) mB[jx] = *(const float4*)(Mp + (9 + jx)*28);
#pragma unroll
      for (int rs = 0; rs < 3; ++rs) {
#pragma unroll
        for (int cs = 0; cs < 3; ++cs) {
          const float* xb = &xh[(rs*10 + p + cs)*28];
          float4 x3 = *(const float4*)(xb + 12);
          float4 x4 = *(const float4*)(xb + 16);
          float4 x5 = *(const float4*)(xb + 20);
          float4 x6 = *(const float4*)(xb + 24);
          float4 t = z[rs*3 + cs];
          fma4(t, mB[0],  x3.x); fma4(t, mB[1],  x3.y); fma4(t, mB[2],  x3.z); fma4(t, mB[3],  x3.w);
          fma4(t, mB[4],  x4.x); fma4(t, mB[5],  x4.y); fma4(t, mB[6],  x4.z); fma4(t, mB[7],  x4.w);
          fma4(t, mB[8],  x5.x); fma4(t, mB[9],  x5.y); fma4(t, mB[10], x5.z); fma4(t, mB[11], x5.w);
          fma4(t, mB[12], x6.x);
          z[rs*3 + cs] = t;
        }
      }
    }
    float* zb = zg + (ry*128 + cx0 + p)*252 + 4*kq;
#pragma unroll
    for (int nb = 0; nb < 9; ++nb)
      *(float4*)(zb + nb*28) = z[nb];
  }
}

// ---------------------------------------------------------------------------
// K2: combine. One thread per hi-res pixel; no LDS, no barriers.
// ---------------------------------------------------------------------------
__global__ __launch_bounds__(256) void comb(
    const float* __restrict__ f4, const float* __restrict__ f6,
    const float* __restrict__ sw, const float* __restrict__ zg,
    float* __restrict__ out) {
  const int n  = blockIdx.x * 256 + threadIdx.x;
  const int Yh = n >> 9, Xh = n & 511;
  const int ry = Yh >> 2, cx = Xh >> 2;
  const int dy = Yh & 3,  dx = Xh & 3;

  const float wrT = (dy == 0 && ry != 0)   ? 1.f : 0.f;
  const float wrB = (dy == 3 && ry != 127) ? 1.f : 0.f;
  const float wcL = (dx == 0 && cx != 0)   ? 1.f : 0.f;
  const float wcR = (dx == 3 && cx != 127) ? 1.f : 0.f;

  float A00 = 0.f, A01 = 0.f, A10 = 0.f, A11 = 0.f;
#pragma unroll
  for (int t9 = 0; t9 < 9; ++t9) {
    const int ddy = t9 / 3, ddx = t9 % 3;
    const float wr = (ddy == 0) ? wrT : ((ddy == 2) ? wrB : 0.f);
    const float wc = (ddx == 0) ? wcL : ((ddx == 2) ? wcR : 0.f);
    const float s = sw[t9];
    A00 += (1.f - wr) * (1.f - wc) * s;
    A01 += (1.f - wr) * wc * s;
    A10 += wr * (1.f - wc) * s;
    A11 += wr * wc * s;
  }

  const int pix = ry*128 + cx;
  const float* zb = zg + pix*252;
  const int cnb = (dx == 0) ? 3 : 5;
  const int rnb = (dy == 0) ? 1 : 7;
  const int dnb = ((dy == 0) ? 0 : 6) + ((dx == 0) ? 0 : 2);

  float* o4 = out + n*9;
  float* o6 = out + NPIX*9 + n*13;
  const float* x4 = f4 + pix*9;
  const float* x6 = f6 + pix*13;

#pragma unroll
  for (int kq = 0; kq < 7; ++kq) {
    float4 zC = *(const float4*)(zb + 4*28   + 4*kq);
    float4 z1 = *(const float4*)(zb + cnb*28 + 4*kq);
    float4 z2 = *(const float4*)(zb + rnb*28 + 4*kq);
    float4 z3 = *(const float4*)(zb + dnb*28 + 4*kq);
    float o0 = fmaf(A00, zC.x, fmaf(A01, z1.x, fmaf(A10, z2.x, A11 * z3.x)));
    float o1 = fmaf(A00, zC.y, fmaf(A01, z1.y, fmaf(A10, z2.y, A11 * z3.y)));
    float o2 = fmaf(A00, zC.z, fmaf(A01, z1.z, fmaf(A10, z2.z, A11 * z3.z)));
    float o3 = fmaf(A00, zC.w, fmaf(A01, z1.w, fmaf(A10, z2.w, A11 * z3.w)));
    if (kq < 2) {
      const int b = 4*kq;
      o4[b]   = o0 + x4[b];
      o4[b+1] = o1 + x4[b+1];
      o4[b+2] = o2 + x4[b+2];
      o4[b+3] = o3 + x4[b+3];
    } else if (kq == 2) {
      o4[8] = o0 + x4[8];
    } else if (kq < 6) {
      const int b = 4*(kq - 3);
      o6[b]   = o0 + x6[b];
      o6[b+1] = o1 + x6[b+1];
      o6[b+2] = o2 + x6[b+2];
      o6[b+3] = o3 + x6[b+3];
    } else {
      o6[12] = o0 + x6[12];
    }
  }
}

extern "C" void kernel_launch(void* const* d_in, const int* in_sizes, int n_in,
                              void* d_out, int out_size, void* d_ws, size_t ws_size,
                              hipStream_t stream) {
  const float* f4  = (const float*)d_in[0];
  const float* f6  = (const float*)d_in[1];
  const float* sw  = (const float*)d_in[2];
  const float* tpw = (const float*)d_in[3];
  float* coef = (float*)d_ws;                 // 13552 floats (pad to 16384)
  float* zg   = (float*)d_ws + 16384;         // 16384*252 floats = 16.5 MB
  float* out  = (float*)d_out;

  hipLaunchKernelGGL(w3j_init, dim3(8), dim3(256), 0, stream, tpw, coef);
  hipLaunchKernelGGL(zcalc, dim3(2048), dim3(128), 0, stream, f4, f6, coef, zg);
  hipLaunchKernelGGL(comb, dim3(1024), dim3(256), 0, stream, f4, f6, sw, zg, out);
}

// Round 10
// 55.002 us; speedup vs baseline: 3.7223x; 1.8575x over previous
//
#include <hip/hip_runtime.h>

#define NPIX (512*512)

// ---------------------------------------------------------------------------
// Init kernel: coef[path][a][b][kq] = 0.5 * tp_w * Cr  (padded k-runs: 12/16).
// Path offsets (floats): {0,972,2268,3672,5544,6948,8820,10848}, 13552 total.
// ---------------------------------------------------------------------------

static __device__ __forceinline__ int qcol(int l, int c, int* row, double* re, double* im) {
  const double S = 0.70710678118654752440;
  int p = c - l;
  if (p == 0) { row[0] = l; re[0] = 1.0; im[0] = 0.0; return 1; }
  if (p > 0) {
    row[0] = l - p; re[0] = S;                 im[0] = 0.0;
    row[1] = l + p; re[1] = (p & 1) ? -S : S;  im[1] = 0.0;
    return 2;
  }
  int a = -p;
  row[0] = l - a; re[0] = 0.0; im[0] = -S;
  row[1] = l + a; re[1] = 0.0; im[1] = (a & 1) ? -S : S;
  return 2;
}

__global__ void w3j_init(const float* __restrict__ tpw, float* __restrict__ coef) {
  __shared__ double sC[13*13*13];
  __shared__ double sfact[20];
  const int p = blockIdx.x;
  const int la = (p & 4) ? 6 : 4, lb = (p & 2) ? 6 : 4, lc = (p & 1) ? 6 : 4;
  const int na = 2*la+1, nb = 2*lb+1, nc = 2*lc+1, ncp = (nc + 3) & ~3;
  if (threadIdx.x == 0) {
    double f = 1.0; sfact[0] = 1.0;
    for (int i = 1; i < 20; ++i) { f *= (double)i; sfact[i] = f; }
  }
  int off = 0;
  for (int q = 0; q < p; ++q)
    off += ((q&4)?13:9) * ((q&2)?13:9) * ((q&1)?16:12);
  for (int e = threadIdx.x; e < na*nb*nc; e += blockDim.x) sC[e] = 0.0;
  __syncthreads();
  for (int e = threadIdx.x; e < na*nb; e += blockDim.x) {
    int i = e / nb, j = e % nb;
    int m1 = i - la, m2 = j - lb, m3 = m1 + m2;
    if (m3 < -lc || m3 > lc) continue;
    double pre = sqrt((2.0*lc + 1.0) * sfact[lc+la-lb] * sfact[lc-la+lb] * sfact[la+lb-lc] / sfact[la+lb+lc+1]);
    pre *= sqrt(sfact[lc+m3]*sfact[lc-m3]*sfact[la-m1]*sfact[la+m1]*sfact[lb-m2]*sfact[lb+m2]);
    double s = 0.0;
    for (int k = 0; k <= la + lb - lc; ++k) {
      int d2 = la - m1 - k, d3 = lb + m2 - k, d4 = lc - lb + m1 + k, d5 = lc - la - m2 + k;
      if (d2 < 0 || d3 < 0 || d4 < 0 || d5 < 0) continue;
      s += ((k & 1) ? -1.0 : 1.0) /
           (sfact[k]*sfact[la+lb-lc-k]*sfact[d2]*sfact[d3]*sfact[d4]*sfact[d5]);
    }
    sC[(i*nb + j)*nc + (lc + m3)] = pre * s;
  }
  __syncthreads();
  const double PH = (((la/2)&1)?-1.0:1.0)*(((lb/2)&1)?-1.0:1.0)*(((lc/2)&1)?-1.0:1.0);
  const double scale = 0.5 * (double)tpw[p] * PH;
  for (int e = threadIdx.x; e < na*nb*ncp; e += blockDim.x) {
    int a = e / (nb*ncp), rem = e % (nb*ncp), b = rem / ncp, c = rem % ncp;
    float val = 0.0f;
    if (c < nc) {
      int r1[2]; double u1r[2], u1i[2]; int n1 = qcol(la, a, r1, u1r, u1i);
      int r2[2]; double u2r[2], u2i[2]; int n2 = qcol(lb, b, r2, u2r, u2i);
      int r3[2]; double u3r[2], u3i[2]; int n3 = qcol(lc, c, r3, u3r, u3i);
      double acc = 0.0;
      for (int u = 0; u < n1; ++u)
        for (int v = 0; v < n2; ++v) {
          double Rr = u1r[u]*u2r[v] - u1i[u]*u2i[v];
          double Ri = u1r[u]*u2i[v] + u1i[u]*u2r[v];
          for (int w = 0; w < n3; ++w) {
            double cv = sC[(r1[u]*nb + r2[v])*nc + r3[w]];
            acc += (Rr*u3r[w] + Ri*u3i[w]) * cv;
          }
        }
      val = (float)(scale * acc);
    }
    coef[off + e] = val;
  }
}

static __device__ __forceinline__ void fma4(float4& a, const float4 c, const float s) {
  a.x = fmaf(c.x, s, a.x); a.y = fmaf(c.y, s, a.y);
  a.z = fmaf(c.z, s, a.z); a.w = fmaf(c.w, s, a.w);
}

// ---------------------------------------------------------------------------
// Fused main kernel. 256 thr, 16 low-res pixels/block, grid 1024. LDS 47 KB.
//  P1 (154 thr): M = C.x, C in <=5-quad chunks (fenced -> low VGPR), M->LDS.
//  P2 (224 thr = 16p x 7kq x 2h): z for 4-5 neighbors each, M chunked.
//  z -> LDS (aliased onto dead Mf region after barrier).
//  Combine (256 thr = 16p x 16sub): A-weights (r8 formula), residual, store.
// ---------------------------------------------------------------------------
__global__ __launch_bounds__(256, 1) void eqconv_main(
    const float* __restrict__ f4, const float* __restrict__ f6,
    const float* __restrict__ sw, const float* __restrict__ coef,
    float* __restrict__ out) {
  __shared__ float Mf[16 * 620];   // 39680 B; words [0,4032) reused for z
  __shared__ float xh[3*18*28];    // 6048 B packed halo
  __shared__ float xT[22*16];      // 1408 B transposed center row

  const int tid = threadIdx.x;
  const int ry  = blockIdx.x >> 3;
  const int cx0 = (blockIdx.x & 7) * 16;

  // ---- stage halo (packed-28; pads zeroed) + transposed center row ----
  for (int e = tid; e < 1188; e += 256) {      // 3*18*22
    int r = e / 396, rem = e - r*396;
    int c = rem / 22, w = rem - c*22;
    int rr = min(127, max(0, ry - 1 + r));
    int cc = min(127, max(0, cx0 - 1 + c));
    float v = (w < 9) ? f4[(rr*128 + cc)*9 + w] : f6[(rr*128 + cc)*13 + (w - 9)];
    xh[(r*18 + c)*28 + (w < 9 ? w : w + 3)] = v;
  }
  for (int e = tid; e < 324; e += 256) {       // zero pad slots 9,10,11,25,26,27
    int pix = e / 6, s = e - pix*6;
    xh[pix*28 + (s < 3 ? 9 + s : 22 + s)] = 0.f;
  }
  for (int e = tid; e < 352; e += 256) {       // xT[c][p]
    int c = e >> 4, p = e & 15;
    int pix = ry*128 + cx0 + p;
    xT[c*16 + p] = (c < 9) ? f4[pix*9 + c] : f6[pix*13 + (c - 9)];
  }
  __syncthreads();

  // ---------------- P1: M = C . x  (chunked C, fenced) ----------------
  if (tid < 154) {
    int cls, jj, kqc;
    if (tid < 27)       { cls = 0; jj = tid / 3;         kqc = tid % 3; }
    else if (tid < 63)  { cls = 1; jj = (tid - 27) / 4;  kqc = (tid - 27) % 4; }
    else if (tid < 102) { cls = 2; jj = (tid - 63) / 3;  kqc = (tid - 63) % 3; }
    else                { cls = 3; jj = (tid - 102) / 4; kqc = (tid - 102) % 4; }
    const int ncp  = (cls == 0 || cls == 2) ? 12 : 16;
    const int str  = (cls == 0) ? 108 : (cls == 1) ? 144 : (cls == 2) ? 156 : 208;
    const int off4 = (cls == 0) ? 0    : (cls == 1) ? 972  : (cls == 2) ? 2268 : 3672;
    const int off6 = (cls == 0) ? 5544 : (cls == 1) ? 6948 : (cls == 2) ? 8820 : 10848;
    const int base4 = off4 + jj*ncp + 4*kqc;
    const int base6 = off6 + jj*ncp + 4*kqc;
    const int j   = (cls >= 2) ? 9 + jj : jj;
    const int kqu = (cls == 0 || cls == 2) ? kqc : 3 + kqc;
    const int mo  = j*28 + kqu*4;

#define P1CHUNK(BASE, I0, LEN, XOFF) { \
    float4 cc[LEN]; \
    _Pragma("unroll") \
    for (int t = 0; t < (LEN); ++t) cc[t] = *(const float4*)(coef + (BASE) + ((I0) + t)*str); \
    _Pragma("unroll") \
    for (int t = 0; t < (LEN); ++t) { \
      const int fi = (XOFF) + (I0) + t; \
      float4 xa = *(const float4*)(&xT[fi*16 + half*8]); \
      float4 xb = *(const float4*)(&xT[fi*16 + half*8 + 4]); \
      fma4(acc[0], cc[t], xa.x); fma4(acc[1], cc[t], xa.y); \
      fma4(acc[2], cc[t], xa.z); fma4(acc[3], cc[t], xa.w); \
      fma4(acc[4], cc[t], xb.x); fma4(acc[5], cc[t], xb.y); \
      fma4(acc[6], cc[t], xb.z); fma4(acc[7], cc[t], xb.w); \
    } \
    asm volatile("" ::: "memory"); }

    for (int half = 0; half < 2; ++half) {
      float4 acc[8];
#pragma unroll
      for (int p8 = 0; p8 < 8; ++p8) acc[p8] = make_float4(0.f, 0.f, 0.f, 0.f);
      P1CHUNK(base4, 0, 4, 0)
      P1CHUNK(base4, 4, 5, 0)
      P1CHUNK(base6, 0, 4, 9)
      P1CHUNK(base6, 4, 4, 9)
      P1CHUNK(base6, 8, 5, 9)
#pragma unroll
      for (int p8 = 0; p8 < 8; ++p8)
        *(float4*)(&Mf[(half*8 + p8)*620 + mo]) = acc[p8];
    }
#undef P1CHUNK
  }
  __syncthreads();

  // ---------------- P2: z for 4-5 neighbors per unit (p, kq, h) ----------------
  const int p2p = tid >> 4;
  const int kq8 = (tid >> 1) & 7;
  const int h   = tid & 1;
  const bool act = (kq8 < 7);
  const int cnt = 5 - h;             // h=0: nb 0..4, h=1: nb 5..8

  float4 z5[5];
#pragma unroll
  for (int u = 0; u < 5; ++u) z5[u] = make_float4(0.f, 0.f, 0.f, 0.f);

  int xoff[5];
#pragma unroll
  for (int u = 0; u < 5; ++u) {
    int nb = h*5 + u; if (nb > 8) nb = 8;
    int rs = nb / 3, cs2 = nb - rs*3;
    xoff[u] = (rs*18 + p2p + cs2)*28;
  }
  const int mbase = p2p*620 + 4*kq8;

#define P2CHUNK4(JB, XQ) { \
    float4 mm[4]; \
    _Pragma("unroll") \
    for (int t = 0; t < 4; ++t) mm[t] = *(const float4*)(&Mf[mbase + ((JB) + t)*28]); \
    _Pragma("unroll") \
    for (int u = 0; u < 5; ++u) if (u < cnt) { \
      float4 xq = *(const float4*)(&xh[xoff[u] + (XQ)]); \
      fma4(z5[u], mm[0], xq.x); fma4(z5[u], mm[1], xq.y); \
      fma4(z5[u], mm[2], xq.z); fma4(z5[u], mm[3], xq.w); \
    } \
    asm volatile("" ::: "memory"); }

#define P2CHUNK1(JB, XQ) { \
    float4 m0 = *(const float4*)(&Mf[mbase + (JB)*28]); \
    _Pragma("unroll") \
    for (int u = 0; u < 5; ++u) if (u < cnt) { \
      float4 xq = *(const float4*)(&xh[xoff[u] + (XQ)]); \
      fma4(z5[u], m0, xq.x); \
    } \
    asm volatile("" ::: "memory"); }

  if (act) {
    P2CHUNK4(0, 0)
    P2CHUNK4(4, 4)
    P2CHUNK1(8, 8)
    P2CHUNK4(9, 12)
    P2CHUNK4(13, 16)
    P2CHUNK4(17, 20)
    P2CHUNK1(21, 24)
  }
#undef P2CHUNK4
#undef P2CHUNK1
  __syncthreads();      // all M reads done -> Mf words [0,4032) become z store

  if (act) {
#pragma unroll
    for (int u = 0; u < 5; ++u)
      if (u < cnt)
        *(float4*)(&Mf[p2p*252 + (h*5 + u)*28 + kq8*4]) = z5[u];
  }
  __syncthreads();

  // ---------------- combine: thread = (p, subpixel) ----------------
  {
    const int p   = tid >> 4;
    const int sub = tid & 15;
    const int dy  = sub >> 2, dx = sub & 3;
    const int cx  = cx0 + p;

    const float wrT = (dy == 0 && ry != 0)   ? 1.f : 0.f;
    const float wrB = (dy == 3 && ry != 127) ? 1.f : 0.f;
    const float wcL = (dx == 0 && cx != 0)   ? 1.f : 0.f;
    const float wcR = (dx == 3 && cx != 127) ? 1.f : 0.f;

    float A00 = 0.f, A01 = 0.f, A10 = 0.f, A11 = 0.f;
#pragma unroll
    for (int t9 = 0; t9 < 9; ++t9) {
      const int ddy = t9 / 3, ddx = t9 % 3;
      const float wr = (ddy == 0) ? wrT : ((ddy == 2) ? wrB : 0.f);
      const float wc = (ddx == 0) ? wcL : ((ddx == 2) ? wcR : 0.f);
      const float s = sw[t9];
      A00 += (1.f - wr) * (1.f - wc) * s;
      A01 += (1.f - wr) * wc * s;
      A10 += wr * (1.f - wc) * s;
      A11 += wr * wc * s;
    }

    const int cnb = (dx == 0) ? 3 : 5;
    const int rnb = (dy == 0) ? 1 : 7;
    const int dnb = ((dy == 0) ? 0 : 6) + ((dx == 0) ? 0 : 2);
    const int zb  = p*252;
    const int n   = (ry*4 + dy)*512 + cx*4 + dx;
    float* o4 = out + n*9;
    float* o6 = out + NPIX*9 + n*13;

#pragma unroll
    for (int kq = 0; kq < 7; ++kq) {
      float4 zC = *(const float4*)(&Mf[zb + 112      + 4*kq]);
      float4 z1 = *(const float4*)(&Mf[zb + cnb*28   + 4*kq]);
      float4 z2 = *(const float4*)(&Mf[zb + rnb*28   + 4*kq]);
      float4 z3 = *(const float4*)(&Mf[zb + dnb*28   + 4*kq]);
      float4 xr = *(const float4*)(&xh[(19 + p)*28   + 4*kq]);
      float o0 = fmaf(A00, zC.x, fmaf(A01, z1.x, fmaf(A10, z2.x, fmaf(A11, z3.x, xr.x))));
      float o1 = fmaf(A00, zC.y, fmaf(A01, z1.y, fmaf(A10, z2.y, fmaf(A11, z3.y, xr.y))));
      float o2 = fmaf(A00, zC.z, fmaf(A01, z1.z, fmaf(A10, z2.z, fmaf(A11, z3.z, xr.z))));
      float o3 = fmaf(A00, zC.w, fmaf(A01, z1.w, fmaf(A10, z2.w, fmaf(A11, z3.w, xr.w))));
      if (kq < 2) {
        const int b = 4*kq;
        o4[b] = o0; o4[b+1] = o1; o4[b+2] = o2; o4[b+3] = o3;
      } else if (kq == 2) {
        o4[8] = o0;
      } else if (kq < 6) {
        const int b = 4*(kq - 3);
        o6[b] = o0; o6[b+1] = o1; o6[b+2] = o2; o6[b+3] = o3;
      } else {
        o6[12] = o0;
      }
    }
  }
}

extern "C" void kernel_launch(void* const* d_in, const int* in_sizes, int n_in,
                              void* d_out, int out_size, void* d_ws, size_t ws_size,
                              hipStream_t stream) {
  const float* f4  = (const float*)d_in[0];
  const float* f6  = (const float*)d_in[1];
  const float* sw  = (const float*)d_in[2];
  const float* tpw = (const float*)d_in[3];
  float* coef = (float*)d_ws;
  float* out  = (float*)d_out;

  hipLaunchKernelGGL(w3j_init, dim3(8), dim3(256), 0, stream, tpw, coef);
  hipLaunchKernelGGL(eqconv_main, dim3(1024), dim3(256), 0, stream,
                     f4, f6, sw, coef, out);
}